// Round 3
// baseline (289.376 us; speedup 1.0000x reference)
//
#include <hip/hip_runtime.h>

#define S_TOT 16384
#define DD 15
#define CC 16
#define WW 12
#define NITER (WW + CC)   // 28: iters s=0..28, cell1 for s<28, cell2 for 12<s<=28
#define NGRP 15
#define L2E  1.4426950408889634f
#define L2E2 2.8853900817779268f

typedef __attribute__((ext_vector_type(8))) short short8v;
typedef __attribute__((ext_vector_type(4))) float f32x4;

__device__ __forceinline__ float rcp_(float x){ return __builtin_amdgcn_rcpf(x); }
__device__ __forceinline__ float ex2_(float x){
#if __has_builtin(__builtin_amdgcn_exp2f)
  return __builtin_amdgcn_exp2f(x);
#else
  return exp2f(x);
#endif
}
__device__ __forceinline__ short f2bf(float f){
  unsigned u = __float_as_uint(f);
  return (short)((u + 0x7FFFu + ((u>>16)&1u)) >> 16);
}
__device__ __forceinline__ float bf2f(short s){
  return __uint_as_float(((unsigned)(unsigned short)s)<<16);
}

// dynamic LDS layout (bytes)
#define OFF_W    0        // short[4096*16]   131072  W_ih bf16, k15 = bias (all pre-scaled by log2e / 2log2e)
#define OFF_U16  131072   // float[4096]      16384   phase1: m2 partials; main: whh float4 per unit
#define OFF_XBF  147456   // short[4*30*16]   3840    x rows bf16, k15 = 1.0
#define OFF_FBF  151296   // short[4*17*16]   2176    forecast rows bf16 (row 16 = zeros), k15 = 1.0
#define OFF_M2S  153472   // float[15*16]     960
#define OFF_CFS  154432   // float[16]        64
#define OFF_PART 154496   // float[2][4][32]  1024    per-wave partials, double-buffered
#define SMEM_TOT 155520

extern "C" __global__ void __launch_bounds__(1024)
lstm_all_k(const float* __restrict__ x, const float* __restrict__ W_ih,
           const float* __restrict__ W_hh, const float* __restrict__ b_ih,
           const float* __restrict__ b_hh, const float* __restrict__ W_hr,
           const float* __restrict__ Wf1, const float* __restrict__ bf1,
           const float* __restrict__ Wf2, const float* __restrict__ bf2,
           float* __restrict__ out) {
  extern __shared__ char smem[];
  short* Wl  = (short*)(smem + OFF_W);
  float* U16 = (float*)(smem + OFF_U16);
  short* xbf = (short*)(smem + OFF_XBF);
  short* fbf = (short*)(smem + OFF_FBF);
  float* m2s = (float*)(smem + OFF_M2S);
  float* cfs = (float*)(smem + OFF_CFS);
  float* part= (float*)(smem + OFF_PART);

  const int j = threadIdx.x;
  const int l = j & 63, wid = j >> 6;
  const int blk = blockIdx.x;

  // ---------------- phase 1: stage xbf, zero fbf, stage W (bf16, bias in k15), m2 MFMA partials
  for (int idx = j; idx < 4*30*16; idx += 1024) {
    int c = idx / 480, rr = idx % 480, row = rr >> 4, k = rr & 15;
    int t = (blk*4 + c)*CC - WW + row;
    float v;
    if (k == 15) v = 1.0f;
    else v = (t >= 0 && t < S_TOT) ? x[t*DD + k] : 0.0f;
    xbf[idx] = f2bf(v);
  }
  for (int idx = j; idx < 4*17*16; idx += 1024) fbf[idx] = 0;
  for (int g = 0; g < 4; ++g) {
    int row = (g << 10) + j;
    float sc = (g == 2) ? L2E2 : L2E;
    short* dst = Wl + row*16;
    const float* src = W_ih + row*DD;
#pragma unroll
    for (int k = 0; k < DD; ++k) dst[k] = f2bf(src[k]*sc);
    dst[15] = f2bf((b_ih[row] + b_hh[row])*sc);
  }
  {
    // M2 = Wf2 @ [Wf1 | bf1] via MFMA: rows = Wf2 rows (pad 16th), cols 0..14 = Wf1 cols, col 15 = bf1
    f32x4 acc = {0.f,0.f,0.f,0.f};
    const int i = l & 15;
    for (int t = 0; t < 8; ++t) {
      int kb = wid*256 + t*32 + (l>>4)*8;
      short8v a = (short8v)0, b = (short8v)0;
      if (i < 15) {
        const float* ap = Wf2 + i*4096 + kb;
#pragma unroll
        for (int e = 0; e < 8; ++e) a[e] = f2bf(ap[e]);
      }
#pragma unroll
      for (int e = 0; e < 8; ++e) {
        int k = kb + e;
        float v = (i < 15) ? Wf1[k*DD + i] : bf1[k];
        b[e] = f2bf(v);
      }
      acc = __builtin_amdgcn_mfma_f32_16x16x32_bf16(a, b, acc, 0, 0, 0);
    }
    float* mp = U16 + wid*256 + (l&15)*16 + (l>>4)*4;
#pragma unroll
    for (int r = 0; r < 4; ++r) mp[r] = acc[r];
  }
  __syncthreads();

  // ---------------- phase 2: reduce m2 partials
  if (j < 256) {
    int col = j >> 4, row = j & 15;
    float s = 0.f;
#pragma unroll
    for (int w = 0; w < 16; ++w) s += U16[w*256 + col*16 + row];
    if (row < 15) {
      if (col < 15) m2s[row*16 + col] = s;
      else cfs[row] = s + bf2[row];
    }
  }
  __syncthreads();

  // ---------------- phase 3: whh (overwrites m2 partials), forecasts -> out + fbf
  {
    f32x4 wv;
    wv.x = W_hh[j]        * L2E;
    wv.y = W_hh[1024 + j] * L2E;
    wv.z = W_hh[2048 + j] * L2E2;
    wv.w = W_hh[3072 + j] * L2E;
    ((f32x4*)U16)[j] = wv;
  }
  if (j < 960) {
    int c = j / 240, r2 = j % 240, tf = r2 / 15, i = r2 % 15;
    const short* xr = xbf + (c*30 + WW + tf)*16;
    float acc = cfs[i];
#pragma unroll
    for (int m = 0; m < DD; ++m) acc = fmaf(m2s[i*16+m], bf2f(xr[m]), acc);
    int tg = (blk*4 + c)*CC + tf;
    out[2*S_TOT + tg*DD + i] = acc;
    fbf[(c*17 + tf)*16 + i] = f2bf(acc);
  } else if (j < 960 + 68) {
    int idx = j - 960, c = idx / 17, row = idx % 17;
    fbf[(c*17 + row)*16 + 15] = (row < 16) ? (short)0x3F80 : (short)0;
  }
  __syncthreads();

  // ---------------- main scan
  const int q = l >> 4;                    // chunk index of this lane's group
  const int T0 = (blk*4 + q)*CC;
  const bool chunk0 = (blk == 0) && (q == 0);
  float wrv[4];
#pragma unroll
  for (int qt = 0; qt < 4; ++qt) wrv[qt] = W_hr[wid*64 + qt*16 + (l&15)];
  f32x4 wv[4];
#pragma unroll
  for (int qt = 0; qt < 4; ++qt) wv[qt] = ((const f32x4*)U16)[wid*64 + qt*16 + (l&15)];

  f32x4 Cg[4][4];
  auto do_group = [&](int grp) {
    int s0 = 2*grp;
    int r = l & 15;
    short8v a = (short8v)0;
    if (l < 32) {
      int half = l >> 4;
      int cch = r >> 2, pp = (r >> 1) & 1, mm = r & 1;
      const short* base;
      if (mm) {
        int tf = s0 + pp - 1 - WW;
        int rowf = ((unsigned)tf < 16u) ? tf : 16;
        base = fbf + (cch*17 + rowf)*16;
      } else {
        base = xbf + (cch*30 + s0 + pp)*16;
      }
      a = *(const short8v*)(base + half*8);
    }
#pragma unroll
    for (int g = 0; g < 4; ++g) {
#pragma unroll
      for (int qt = 0; qt < 4; ++qt) {
        short8v b = (short8v)0;
        if (l < 32) {
          int gate = (g<<10) | (wid<<6) | (qt<<4) | r;
          b = *(const short8v*)(Wl + gate*16 + (l>>4)*8);
        }
        f32x4 z = {0.f,0.f,0.f,0.f};
        Cg[g][qt] = __builtin_amdgcn_mfma_f32_16x16x32_bf16(a, b, z, 0, 0, 0);
      }
    }
  };

  float h = 0.f;
  float cst[4] = {0.f, 0.f, 0.f, 0.f};
  do_group(0);

  for (int grp = 0; grp < NGRP; ++grp) {
#pragma unroll
    for (int pp = 0; pp < 2; ++pp) {
      const int s = 2*grp + pp;
      if (s <= NITER) {
        float p1 = 0.f, p2 = 0.f;
        const bool c2 = (s > WW);
        const bool c1 = (s < NITER);
        if (c2) {
#pragma unroll
          for (int qt = 0; qt < 4; ++qt) {
            float ai = fmaf(wv[qt].x, h, Cg[0][qt][2*pp+1]);
            float af = fmaf(wv[qt].y, h, Cg[1][qt][2*pp+1]);
            float ag = fmaf(wv[qt].z, h, Cg[2][qt][2*pp+1]);
            float ao = fmaf(wv[qt].w, h, Cg[3][qt][2*pp+1]);
            float si = rcp_(1.f + ex2_(-ai));
            float sf = rcp_(1.f + ex2_(-af));
            float tg = fmaf(-2.f, rcp_(1.f + ex2_(ag)), 1.f);
            float so = rcp_(1.f + ex2_(-ao));
            float cn = fmaf(sf, cst[qt], si*tg);
            float tc = fmaf(-2.f, rcp_(1.f + ex2_(cn*L2E2)), 1.f);
            p2 += wrv[qt] * (so * tc);
          }
        }
        if (c1) {
          const float lv = (chunk0 && s < WW) ? 0.f : 1.f;
#pragma unroll
          for (int qt = 0; qt < 4; ++qt) {
            float ai = fmaf(wv[qt].x, h, Cg[0][qt][2*pp]);
            float af = fmaf(wv[qt].y, h, Cg[1][qt][2*pp]);
            float ag = fmaf(wv[qt].z, h, Cg[2][qt][2*pp]);
            float ao = fmaf(wv[qt].w, h, Cg[3][qt][2*pp]);
            float si = rcp_(1.f + ex2_(-ai));
            float sf = rcp_(1.f + ex2_(-af));
            float tg = fmaf(-2.f, rcp_(1.f + ex2_(ag)), 1.f);
            float so = rcp_(1.f + ex2_(-ao));
            float cn = fmaf(sf, cst[qt], si*tg);
            float tc = fmaf(-2.f, rcp_(1.f + ex2_(cn*L2E2)), 1.f);
            cst[qt] = lv * cn;
            p1 += wrv[qt] * (so * tc);
          }
          p1 *= lv;
        }
        if (pp == 1 && grp < NGRP-1) do_group(grp + 1);  // refill Cg after consumption, before tree wait
        // two-level reduction: 16-lane tree -> per-wave slot -> barrier -> 16-wave tree
        float vx = p1, vy = p2;
#pragma unroll
        for (int mm = 1; mm <= 8; mm <<= 1) { vx += __shfl_xor(vx, mm); vy += __shfl_xor(vy, mm); }
        float* pb = part + (s & 1)*128 + q*32;
        if ((l & 15) == 0) { pb[wid*2] = vx; pb[wid*2+1] = vy; }
        __syncthreads();
        float tx = pb[(l&15)*2], ty = pb[(l&15)*2 + 1];
#pragma unroll
        for (int mm = 1; mm <= 8; mm <<= 1) { tx += __shfl_xor(tx, mm); ty += __shfl_xor(ty, mm); }
        h = tx;
        if (wid == 0 && (l & 15) == 0) {
          if (c1 && s >= WW) out[T0 + s - WW] = tx;
          if (c2) out[S_TOT + T0 + s - 1 - WW] = ty;
        }
      }
    }
  }
}

extern "C" void kernel_launch(void* const* d_in, const int* in_sizes, int n_in,
                              void* d_out, int out_size, void* d_ws, size_t ws_size,
                              hipStream_t stream) {
  const float* x    = (const float*)d_in[0];
  const float* W_ih = (const float*)d_in[1];
  const float* W_hh = (const float*)d_in[2];
  const float* b_ih = (const float*)d_in[3];
  const float* b_hh = (const float*)d_in[4];
  const float* W_hr = (const float*)d_in[5];
  const float* Wf1  = (const float*)d_in[6];
  const float* bf1  = (const float*)d_in[7];
  const float* Wf2  = (const float*)d_in[8];
  const float* bf2  = (const float*)d_in[9];
  float* out = (float*)d_out;

  (void)hipFuncSetAttribute((const void*)lstm_all_k,
                            hipFuncAttributeMaxDynamicSharedMemorySize, SMEM_TOT);
  hipLaunchKernelGGL(lstm_all_k, dim3(256), dim3(1024), SMEM_TOT, stream,
                     x, W_ih, W_hh, b_ih, b_hh, W_hr, Wf1, bf1, Wf2, bf2, out);
}

// Round 4
// 182.905 us; speedup vs baseline: 1.5821x; 1.5821x over previous
//
#include <hip/hip_runtime.h>

#define S_TOT 16384
#define DD 15
#define CC 64
#define WW 16
#define L2E  1.4426950408889634f
#define L2E2 2.8853900817779268f

typedef __attribute__((ext_vector_type(8))) short short8v;
typedef __attribute__((ext_vector_type(4))) float f32x4;

__device__ __forceinline__ float rcp_(float x){ return __builtin_amdgcn_rcpf(x); }
__device__ __forceinline__ float ex2_(float x){
#if __has_builtin(__builtin_amdgcn_exp2f)
  return __builtin_amdgcn_exp2f(x);
#else
  return exp2f(x);
#endif
}
__device__ __forceinline__ unsigned short f2bfu(float f){
  unsigned u = __float_as_uint(f);
  return (unsigned short)((u + 0x7FFFu + ((u>>16)&1u)) >> 16);
}
__device__ __forceinline__ float bfu2f(unsigned short s){
  return __uint_as_float(((unsigned)s)<<16);
}

// ---------------- prep: W -> bf16 B-fragment image in ws; M2 partials ----------------
// ws layout: [0,131072) W-frags (65536 ushorts = 8192 pairs x 8)
//            [131072,147456) ws2: 16 x 256 floats (M2/cf partials per k-slice)
__global__ void __launch_bounds__(256)
prep_k(const float* __restrict__ W_ih, const float* __restrict__ b_ih,
       const float* __restrict__ b_hh, const float* __restrict__ Wf1,
       const float* __restrict__ bf1, const float* __restrict__ Wf2,
       unsigned short* __restrict__ wsW, float* __restrict__ ws2) {
  const int blk = blockIdx.x, tid = threadIdx.x;
  if (blk < 16) {
    __shared__ float wf2s[15*256];
    __shared__ float wf1s[256*15];
    __shared__ float bf1s[256];
    const int k0 = blk*256;
    for (int idx = tid; idx < 3840; idx += 256) { int i = idx >> 8, kk = idx & 255; wf2s[i*256+kk] = Wf2[i*4096 + k0 + kk]; }
    for (int idx = tid; idx < 3840; idx += 256) wf1s[idx] = Wf1[k0*15 + idx];
    bf1s[tid] = bf1[k0 + tid];
    __syncthreads();
    if (tid < 240) {
      float acc = 0.f;
      if (tid < 225) {
        int i = tid/15, jj = tid%15;
        for (int kk = 0; kk < 256; ++kk) acc = fmaf(wf2s[i*256+kk], wf1s[kk*15+jj], acc);
      } else {
        int i = tid-225;
        for (int kk = 0; kk < 256; ++kk) acc = fmaf(wf2s[i*256+kk], bf1s[kk], acc);
      }
      ws2[blk*256 + tid] = acc;
    }
  } else {
    // W-frag conversion: pair p = (tile tt = w*16+ct, lane' in [0,32)); 8 bf16 per pair.
    const int pid = (blk-16)*256 + tid;        // [0,1024)
    for (int q = 0; q < 8; ++q) {
      int p = pid*8 + q;
      int tt = p >> 5, lane = p & 31;
      int w = tt >> 4, ct = tt & 15;
      int ks = (lane >> 4)*8, c16 = lane & 15;
      int n = ct*16 + c16, g = n & 3, ul = n >> 2;
      int row = g*1024 + w*64 + ul;
      float sc = (g == 2) ? L2E2 : L2E;
      union { unsigned short us[8]; uint4 v; } u;
#pragma unroll
      for (int e = 0; e < 8; ++e) {
        int k = ks + e;
        float val = (k < 15) ? W_ih[row*15 + k]*sc : (b_ih[row] + b_hh[row])*sc;
        u.us[e] = f2bfu(val);
      }
      *(uint4*)(wsW + p*8) = u.v;
    }
  }
}

// ---------------- scan ----------------
// dynamic LDS layout (bytes):
#define OFF_PRE  0        // per-wave 16 rows x 264 shorts (528B): rows 0..7 xpre, 8..15 fpre. 16 waves.
#define PW_STR   8448
#define OFF_XST  135168   // 80 rows x 16 ushorts = 2560
#define OFF_FST  137728   // 64 rows x 16 ushorts = 2048
#define OFF_M2   139776   // 240 floats (m2s[i*16+m]) + 16 floats cf = 1024
#define OFF_P1   140800   // 2 x 16 floats = 128
#define OFF_P2   140928   // 2 x 16 waves x 8 floats = 1024
#define SMEM_TOT 141952

#define CELL(pi,pf_,pg,po,hv,cv,CN,PV) { \
  float ai = fmaf(whhx, (hv), (pi)); \
  float af = fmaf(whhy, (hv), (pf_)); \
  float ag = fmaf(whhz, (hv), (pg)); \
  float ao = fmaf(whhw, (hv), (po)); \
  float si = rcp_(1.f + ex2_(-ai)); \
  float sf = rcp_(1.f + ex2_(-af)); \
  float tg = fmaf(-2.f, rcp_(1.f + ex2_(ag)), 1.f); \
  float so = rcp_(1.f + ex2_(-ao)); \
  CN = fmaf(sf, (cv), si*tg); \
  float tc = fmaf(-2.f, rcp_(1.f + ex2_((CN)*L2E2)), 1.f); \
  PV = wr*(so*tc); }

extern "C" __global__ void __launch_bounds__(1024, 4)
lstm_scan_k(const float* __restrict__ x, const float* __restrict__ W_hh,
            const float* __restrict__ W_hr, const float* __restrict__ bf2,
            const unsigned short* __restrict__ wsW, const float* __restrict__ ws2,
            float* __restrict__ out) {
  extern __shared__ char smem[];
  unsigned short* xst = (unsigned short*)(smem + OFF_XST);
  unsigned short* fst = (unsigned short*)(smem + OFF_FST);
  float* m2s = (float*)(smem + OFF_M2);
  float* cfs = (float*)(smem + OFF_M2 + 960);
  float* p1b = (float*)(smem + OFF_P1);
  float* p2b = (float*)(smem + OFF_P2);

  const int j = threadIdx.x;
  const int l = j & 63, w = j >> 6;
  const int blk = blockIdx.x;
  const int t0 = blk * CC;
  char* myPre = smem + OFF_PRE + w*PW_STR;

  // ---- phase A: stage x (bf16, k15=1), reduce M2 partials, forecasts -> out + fstage
  for (int idx = j; idx < 80*16; idx += 1024) {
    int r = idx >> 4, k = idx & 15;
    int t = t0 - WW + r;
    float v = (k == 15) ? 1.f : ((t >= 0) ? x[t*DD + k] : 0.f);
    xst[idx] = f2bfu(v);
  }
  if (j < 240) {
    float s = 0.f;
#pragma unroll
    for (int b = 0; b < 16; ++b) s += ws2[b*256 + j];
    if (j < 225) m2s[(j/15)*16 + (j%15)] = s;
    else cfs[j-225] = s + bf2[j-225];
  }
  __syncthreads();
  if (j < 960) {
    int tf = j/15, i = j%15;
    const unsigned short* xr = xst + (WW + tf)*16;
    float acc = cfs[i];
#pragma unroll
    for (int m = 0; m < DD; ++m) acc = fmaf(m2s[i*16+m], bfu2f(xr[m]), acc);
    out[2*S_TOT + (t0 + tf)*DD + i] = acc;
    fst[tf*16 + i] = f2bfu(acc);
  } else {
    fst[(j - 960)*16 + 15] = 0x3F80;  // 1.0 bias slot
  }

  // ---- per-thread recurrent params + B-frags (while barrier pending is fine; reads are global)
  const float whhx = W_hh[j]*L2E, whhy = W_hh[1024+j]*L2E,
              whhz = W_hh[2048+j]*L2E2, whhw = W_hh[3072+j]*L2E;
  const float wr = W_hr[j];

  short8v bfrag[16];
#pragma unroll
  for (int ct = 0; ct < 16; ++ct) {
    short8v v = (short8v)0;
    if (l < 32) v = ((const short8v*)wsW)[(w*16 + ct)*32 + l];
    bfrag[ct] = v;
  }
  __syncthreads();

  const int r16 = l & 15, hk = l >> 4;

  // window MFMA: one M=16 tile -> per-wave pre buffer (rows 0..7 = stream0, 8..15 = stream1)
  auto run_mfma = [&](int m, bool warmw) {
    short8v a = (short8v)0;
    if (l < 32) {
      const char* abase;
      if (warmw) abase = (const char*)(xst + r16*16);
      else abase = (r16 < 8) ? (const char*)(xst + (WW + 8*m + r16)*16)
                             : (const char*)(fst + (8*m + r16 - 8)*16);
      a = *(const short8v*)(abase + hk*16);
    }
#pragma unroll
    for (int ct = 0; ct < 16; ++ct) {
      f32x4 z = {0.f, 0.f, 0.f, 0.f};
      f32x4 acc = __builtin_amdgcn_mfma_f32_16x16x32_bf16(a, bfrag[ct], z, 0, 0, 0);
      char* cb = myPre + (ct*16 + r16)*2;
#pragma unroll
      for (int r2 = 0; r2 < 4; ++r2) {
        int row = 4*hk + r2;
        *(unsigned short*)(cb + row*528) = f2bfu(acc[r2]);
      }
    }
  };

  float h = 0.f, cst = 0.f;
  float hh[8], chh[8];
  int pb = 0;

  // ---- warm window: 16 steps (rows 0..15), no outputs; block 0 zero-forced
  {
    run_mfma(0, true);
    const float lv = (blk == 0) ? 0.f : 1.f;
#pragma unroll
    for (int half = 0; half < 2; ++half) {
      uint2 pf[8];
#pragma unroll
      for (int r = 0; r < 8; ++r) pf[r] = *(const uint2*)(myPre + (half*8 + r)*528 + l*8);
#pragma unroll
      for (int r = 0; r < 8; ++r) {
        float pi = __uint_as_float(pf[r].x << 16);
        float pfv = __uint_as_float(pf[r].x & 0xFFFF0000u);
        float pg = __uint_as_float(pf[r].y << 16);
        float po = __uint_as_float(pf[r].y & 0xFFFF0000u);
        float cn, p1;
        CELL(pi, pfv, pg, po, h, cst, cn, p1);
        cst = lv * cn;
        p1 *= lv;
#pragma unroll
        for (int off = 32; off; off >>= 1) p1 += __shfl_xor(p1, off);
        if (l == 0) p1b[pb*16 + w] = p1;
        __syncthreads();
        const f32x4* pp = (const f32x4*)(p1b + pb*16);
        f32x4 q0 = pp[0], q1 = pp[1], q2 = pp[2], q3 = pp[3];
        h = (q0.x+q0.y+q0.z+q0.w) + (q1.x+q1.y+q1.z+q1.w)
          + (q2.x+q2.y+q2.z+q2.w) + (q3.x+q3.y+q3.z+q3.w);
        pb ^= 1;
      }
    }
  }

  // ---- main: 8 windows x 8 steps; cell2 batched per window, published one window late
  for (int m = 0; m < 8; ++m) {
    run_mfma(m, false);
    uint2 pf[8];
#pragma unroll
    for (int r = 0; r < 8; ++r) pf[r] = *(const uint2*)(myPre + r*528 + l*8);
#pragma unroll
    for (int r = 0; r < 8; ++r) {
      float pi = __uint_as_float(pf[r].x << 16);
      float pfv = __uint_as_float(pf[r].x & 0xFFFF0000u);
      float pg = __uint_as_float(pf[r].y << 16);
      float po = __uint_as_float(pf[r].y & 0xFFFF0000u);
      float cn, p1;
      CELL(pi, pfv, pg, po, h, cst, cn, p1);
      cst = cn; chh[r] = cn;
#pragma unroll
      for (int off = 32; off; off >>= 1) p1 += __shfl_xor(p1, off);
      if (l == 0) p1b[pb*16 + w] = p1;
      __syncthreads();
      if (r == 0 && m > 0 && j < 8) {     // publish previous window's fprog
        float s = 0.f;
#pragma unroll
        for (int w2 = 0; w2 < 16; ++w2) s += p2b[(((m-1)&1)*16 + w2)*8 + j];
        out[S_TOT + t0 + 8*(m-1) + j] = s;
      }
      const f32x4* pp = (const f32x4*)(p1b + pb*16);
      f32x4 q0 = pp[0], q1 = pp[1], q2 = pp[2], q3 = pp[3];
      h = (q0.x+q0.y+q0.z+q0.w) + (q1.x+q1.y+q1.z+q1.w)
        + (q2.x+q2.y+q2.z+q2.w) + (q3.x+q3.y+q3.z+q3.w);
      hh[r] = h;
      if (j == 0) out[t0 + 8*m + r] = h;
      pb ^= 1;
    }
    // cell2 batch: 8 independent evals from history + fpre rows 8..15
    float p2v[8];
#pragma unroll
    for (int r = 0; r < 8; ++r) {
      uint2 qv = *(const uint2*)(myPre + (8 + r)*528 + l*8);
      float pi = __uint_as_float(qv.x << 16);
      float pfv = __uint_as_float(qv.x & 0xFFFF0000u);
      float pg = __uint_as_float(qv.y << 16);
      float po = __uint_as_float(qv.y & 0xFFFF0000u);
      float cn, p2;
      CELL(pi, pfv, pg, po, hh[r], chh[r], cn, p2);
      p2v[r] = p2;
    }
#pragma unroll
    for (int r = 0; r < 8; ++r) {
#pragma unroll
      for (int off = 32; off; off >>= 1) p2v[r] += __shfl_xor(p2v[r], off);
    }
    if (l == 0) {
#pragma unroll
      for (int r = 0; r < 8; ++r) p2b[((m&1)*16 + w)*8 + r] = p2v[r];
    }
  }
  // epilogue: publish window 7's fprog
  __syncthreads();
  if (j < 8) {
    float s = 0.f;
#pragma unroll
    for (int w2 = 0; w2 < 16; ++w2) s += p2b[((7&1)*16 + w2)*8 + j];
    out[S_TOT + t0 + 56 + j] = s;
  }
}

extern "C" void kernel_launch(void* const* d_in, const int* in_sizes, int n_in,
                              void* d_out, int out_size, void* d_ws, size_t ws_size,
                              hipStream_t stream) {
  const float* x    = (const float*)d_in[0];
  const float* W_ih = (const float*)d_in[1];
  const float* W_hh = (const float*)d_in[2];
  const float* b_ih = (const float*)d_in[3];
  const float* b_hh = (const float*)d_in[4];
  const float* W_hr = (const float*)d_in[5];
  const float* Wf1  = (const float*)d_in[6];
  const float* bf1  = (const float*)d_in[7];
  const float* Wf2  = (const float*)d_in[8];
  const float* bf2  = (const float*)d_in[9];
  float* out = (float*)d_out;
  unsigned short* wsW = (unsigned short*)d_ws;
  float* ws2 = (float*)((char*)d_ws + 131072);

  hipLaunchKernelGGL(prep_k, dim3(20), dim3(256), 0, stream,
                     W_ih, b_ih, b_hh, Wf1, bf1, Wf2, wsW, ws2);
  (void)hipFuncSetAttribute((const void*)lstm_scan_k,
                            hipFuncAttributeMaxDynamicSharedMemorySize, SMEM_TOT);
  hipLaunchKernelGGL(lstm_scan_k, dim3(256), dim3(1024), SMEM_TOT, stream,
                     x, W_hh, W_hr, bf2, wsW, ws2, out);
}